// Round 12
// baseline (150.432 us; speedup 1.0000x reference)
//
#include <hip/hip_runtime.h>
#include <hip/hip_fp16.h>
#include <math.h>

#define NSAMP 256

typedef _Float16 f16;
typedef _Float16 f16x4 __attribute__((ext_vector_type(4)));
typedef _Float16 f16x8 __attribute__((ext_vector_type(8)));
typedef float    f32x4 __attribute__((ext_vector_type(4)));

// ---------- pre-pass 1: transpose F [32ch][32768vox] -> Ft [vox][32ch] ----------
__global__ __launch_bounds__(256) void transpose_F(
    const float* __restrict__ Fg, float* __restrict__ Ft)
{
    const int j = blockIdx.x * 256 + threadIdx.x;   // voxel id 0..32767
    float4 o[8];
    #pragma unroll
    for (int q = 0; q < 8; ++q) {
        o[q].x = Fg[(size_t)(4*q+0)*32768 + j];
        o[q].y = Fg[(size_t)(4*q+1)*32768 + j];
        o[q].z = Fg[(size_t)(4*q+2)*32768 + j];
        o[q].w = Fg[(size_t)(4*q+3)*32768 + j];
    }
    float4* dst = (float4*)(Ft + (size_t)j * 32);
    #pragma unroll
    for (int q = 0; q < 8; ++q) dst[q] = o[q];
}

// ---------- pre-pass 1b: interleave G1 -> f16x4 per voxel (8B) ----------
// Halves G1t footprint to 16.8MB (mostly L2-resident). g-values are ~±0.05,
// f16 abs err ~3e-5 -> negligible vs 2e-2 output tolerance.
__global__ __launch_bounds__(256) void transpose_G1h(
    const float* __restrict__ G1, f16x4* __restrict__ G1t)
{
    const int v = blockIdx.x * 256 + threadIdx.x;   // 0..2097151
    f16x4 o;
    o[0] = (f16)G1[v];
    o[1] = (f16)G1[2097152 + v];
    o[2] = (f16)G1[2*2097152 + v];
    o[3] = (f16)0.0f;
    G1t[v] = o;
}

// ---------- pre-pass 2: pack layer-1 weights as MFMA B-fragments ----------
// B-frag lane layout for mfma_f32_16x16x32_f16: col j = lane&15,
// k = 8*(lane>>4) + i (i=0..7). Must match A-side LDS read order.
__global__ __launch_bounds__(256) void pack_bfrags(
    const float* __restrict__ Wd1, const float* __restrict__ Wc1,
    f16* __restrict__ Bd, f16* __restrict__ Bc)
{
    const int idx  = threadIdx.x;          // 0..255, single block
    const int nt   = idx >> 6;             // N-tile 0..3
    const int lane = idx & 63;
    const int j    = nt*16 + (lane & 15);
    const int k0   = (lane >> 4) * 8;
    f16x8 vd, vc;
    #pragma unroll
    for (int i = 0; i < 8; ++i) {
        vd[i] = (f16)Wd1[(k0+i)*64 + j];
        vc[i] = (f16)Wc1[(k0+i)*64 + j];
    }
    *(f16x8*)(Bd + ((size_t)(nt*64+lane))*8) = vd;
    *(f16x8*)(Bc + ((size_t)(nt*64+lane))*8) = vc;
}

// ================= K1: gather + MLP, balanced wave->(ray,quarter) ============
// Round-12: block=ray caused a long ramp-down tail (occupancy 24% vs 75%
// static). Waves are independent (own 64 LDS rows, no barriers), so wave wv
// of block b handles quarter wv of ray (b + wv*grid/4) % grid -> each block
// mixes head/tail quarters of 4 rays -> uniform duration. Outputs per-sample
// {masked sigma, rgb logits} to ws; masked sigma=0 => alpha=0 => rgb moot.
__global__ __launch_bounds__(256) __attribute__((amdgpu_waves_per_eu(2, 6)))
void nerf_gather(
    const float* __restrict__ rays_o, const float* __restrict__ rays_d,
    const f16x4* __restrict__ G1t, const float* __restrict__ Ft,
    const float* __restrict__ bd1, const float* __restrict__ Wd2,
    const float* __restrict__ bd2,
    const float* __restrict__ Wc1, const float* __restrict__ bc1,
    const float* __restrict__ Wc2,
    const f16* __restrict__ Bd, const f16* __restrict__ Bc,
    float4* __restrict__ samp)
{
    const float RADIUS = 1.3f;
    const float STEP = 0.0176f;

    const int tid  = threadIdx.x;
    const int lane = tid & 63;
    const int wv   = tid >> 6;

    // wave -> (ray, quarter): quarter = wv, ray mixed across blocks
    int ray = blockIdx.x + wv * (gridDim.x >> 2);
    if (ray >= (int)gridDim.x) ray -= gridDim.x;

    __shared__ __align__(16) f16 feats_lds[256][40];  // 80B rows, wave-private

    // ---- ray setup (wave-uniform) ----
    const float ox = rays_o[ray*3+0], oy = rays_o[ray*3+1], oz = rays_o[ray*3+2];
    const float rdx = rays_d[ray*3+0], rdy = rays_d[ray*3+1], rdz = rays_d[ray*3+2];
    const float rn  = sqrtf(rdx*rdx + rdy*rdy + rdz*rdz);
    const float dxn = rdx/rn, dyn = rdy/rn, dzn = rdz/rn;

    // ---- cube intersection ----
    float sd, inv, t1, t2, tmin, tmax;
    sd = (fabsf(dxn) < 1e-9f) ? 1e-9f : dxn; inv = 1.0f/sd;
    t1 = (-RADIUS - ox)*inv; t2 = (RADIUS - ox)*inv;
    tmin = fminf(t1,t2); tmax = fmaxf(t1,t2);
    sd = (fabsf(dyn) < 1e-9f) ? 1e-9f : dyn; inv = 1.0f/sd;
    t1 = (-RADIUS - oy)*inv; t2 = (RADIUS - oy)*inv;
    tmin = fmaxf(tmin, fminf(t1,t2)); tmax = fminf(tmax, fmaxf(t1,t2));
    sd = (fabsf(dzn) < 1e-9f) ? 1e-9f : dzn; inv = 1.0f/sd;
    t1 = (-RADIUS - oz)*inv; t2 = (RADIUS - oz)*inv;
    tmin = fmaxf(tmin, fminf(t1,t2)); tmax = fminf(tmax, fmaxf(t1,t2));

    const float tnear = fmaxf(tmin, 0.0f);
    const bool  hit   = tmax > tnear;
    const float t     = tnear + STEP * (float)tid;   // sample-in-ray == tid
    const bool  mask  = (t < tmax) && hit;

    if (!__any(mask)) {
        // whole wave masked: zero its 64 samples and exit
        samp[(size_t)ray*NSAMP + tid] = (float4){0.f, 0.f, 0.f, 0.f};
        return;
    }

    // =========================== gather phase ===========================
    float feats[32];
    {
        const float invR = 1.0f / RADIUS;
        const float px = (ox + t*dxn) * invR;
        const float py = (oy + t*dyn) * invR;
        const float pz = (oz + t*dzn) * invR;

        float cox = fminf(fmaxf((px+1.0f)*0.5f*127.0f, 0.0f), 127.0f);
        float coy = fminf(fmaxf((py+1.0f)*0.5f*127.0f, 0.0f), 127.0f);
        float coz = fminf(fmaxf((pz+1.0f)*0.5f*127.0f, 0.0f), 127.0f);
        int x0 = (int)floorf(cox); float fx = cox - (float)x0; int x1 = min(x0+1, 127);
        int y0 = (int)floorf(coy); float fy = coy - (float)y0; int y1 = min(y0+1, 127);
        int z0 = (int)floorf(coz); float fz = coz - (float)z0; int z1 = min(z0+1, 127);

        {
            const float wx0 = 1.0f-fx, wx1 = fx;
            const float wy0 = 1.0f-fy, wy1 = fy;
            const float wz0 = 1.0f-fz, wz1 = fz;
            const float w000 = wx0*wy0*wz0, w100 = wx1*wy0*wz0;
            const float w010 = wx0*wy1*wz0, w110 = wx1*wy1*wz0;
            const float w001 = wx0*wy0*wz1, w101 = wx1*wy0*wz1;
            const float w011 = wx0*wy1*wz1, w111 = wx1*wy1*wz1;
            const int i000 = (z0*128 + y0)*128 + x0;
            const int dxo = x1 - x0;
            const int dyo = (y1 - y0)*128;
            const int dzo = (z1 - z0)*16384;

            const f16x4 v000 = G1t[i000];
            const f16x4 v100 = G1t[i000 + dxo];
            const f16x4 v010 = G1t[i000 + dyo];
            const f16x4 v110 = G1t[i000 + dyo + dxo];
            const f16x4 v001 = G1t[i000 + dzo];
            const f16x4 v101 = G1t[i000 + dzo + dxo];
            const f16x4 v011 = G1t[i000 + dzo + dyo];
            const f16x4 v111 = G1t[i000 + dzo + dyo + dxo];

            float g[3];
            #pragma unroll
            for (int c = 0; c < 3; ++c) {
                g[c] = w000*(float)v000[c] + w100*(float)v100[c]
                     + w010*(float)v010[c] + w110*(float)v110[c]
                     + w001*(float)v001[c] + w101*(float)v101[c]
                     + w011*(float)v011[c] + w111*(float)v111[c];
            }

            cox = fminf(fmaxf((g[0]+1.0f)*0.5f*31.0f, 0.0f), 31.0f);
            coy = fminf(fmaxf((g[1]+1.0f)*0.5f*31.0f, 0.0f), 31.0f);
            coz = fminf(fmaxf((g[2]+1.0f)*0.5f*31.0f, 0.0f), 31.0f);
            x0 = (int)floorf(cox); fx = cox - (float)x0; x1 = min(x0+1, 31);
            y0 = (int)floorf(coy); fy = coy - (float)y0; y1 = min(y0+1, 31);
            z0 = (int)floorf(coz); fz = coz - (float)z0; z1 = min(z0+1, 31);
        }

        #pragma unroll
        for (int c = 0; c < 32; ++c) feats[c] = 0.0f;
        {
            const float wx0 = 1.0f-fx, wx1 = fx;
            const float wy0 = 1.0f-fy, wy1 = fy;
            const float wz0 = 1.0f-fz, wz1 = fz;
            const int j000 = (z0*32 + y0)*32 + x0;
            const int dxo = x1 - x0;
            const int dyo = (y1 - y0)*32;
            const int dzo = (z1 - z0)*1024;

            const int   jidx[8] = { j000,           j000+dxo,
                                    j000+dyo,       j000+dyo+dxo,
                                    j000+dzo,       j000+dzo+dxo,
                                    j000+dzo+dyo,   j000+dzo+dyo+dxo };
            const float jwt[8]  = { wx0*wy0*wz0, wx1*wy0*wz0,
                                    wx0*wy1*wz0, wx1*wy1*wz0,
                                    wx0*wy0*wz1, wx1*wy0*wz1,
                                    wx0*wy1*wz1, wx1*wy1*wz1 };

            #pragma unroll
            for (int corner = 0; corner < 8; ++corner) {
                const float4* fp = (const float4*)(Ft + (size_t)jidx[corner] * 32);
                const float w = jwt[corner];
                #pragma unroll
                for (int q = 0; q < 8; ++q) {
                    const float4 v = fp[q];
                    feats[4*q+0] += w * v.x;
                    feats[4*q+1] += w * v.y;
                    feats[4*q+2] += w * v.z;
                    feats[4*q+3] += w * v.w;
                }
            }
        }
    }

    // ---- stage feats to LDS as f16 (wave-private rows; no barrier needed) ----
    #pragma unroll
    for (int gq = 0; gq < 4; ++gq) {
        f16x8 h;
        #pragma unroll
        for (int i = 0; i < 8; ++i) h[i] = (f16)feats[gq*8+i];
        *(f16x8*)&feats_lds[tid][gq*8] = h;
    }

    // ---- MFMA phase (wave computes its own 64 samples) ----
    {
        const int lane15 = lane & 15;
        const int laneg  = lane >> 4;

        float bias_d[4], bias_c[4], wd2v[4];
        float wc2r[4], wc2g[4], wc2b[4];
        #pragma unroll
        for (int nt = 0; nt < 4; ++nt) {
            const int j = nt*16 + lane15;
            bias_d[nt] = bd1[j];
            bias_c[nt] = bc1[j] + dxn*Wc1[32*64+j] + dyn*Wc1[33*64+j] + dzn*Wc1[34*64+j];
            wd2v[nt]   = Wd2[j];
            wc2r[nt]   = Wc2[j*3+0];
            wc2g[nt]   = Wc2[j*3+1];
            wc2b[nt]   = Wc2[j*3+2];
        }
        f16x8 bdf[4], bcf[4];
        #pragma unroll
        for (int nt = 0; nt < 4; ++nt) {
            bdf[nt] = *(const f16x8*)(Bd + ((size_t)(nt*64+lane))*8);
            bcf[nt] = *(const f16x8*)(Bc + ((size_t)(nt*64+lane))*8);
        }
        const float bd2v = bd2[0];

        #pragma unroll
        for (int mt = 0; mt < 4; ++mt) {
            const int arow = wv*64 + mt*16 + lane15;
            const f16x8 af = *(const f16x8*)&feats_lds[arow][laneg*8];

            f32x4 accd[4], accc[4];
            #pragma unroll
            for (int nt = 0; nt < 4; ++nt) {
                const float bdv = bias_d[nt], bcv = bias_c[nt];
                accd[nt] = (f32x4){bdv, bdv, bdv, bdv};
                accc[nt] = (f32x4){bcv, bcv, bcv, bcv};
            }
            #pragma unroll
            for (int nt = 0; nt < 4; ++nt) {
                accd[nt] = __builtin_amdgcn_mfma_f32_16x16x32_f16(af, bdf[nt], accd[nt], 0, 0, 0);
                accc[nt] = __builtin_amdgcn_mfma_f32_16x16x32_f16(af, bcf[nt], accc[nt], 0, 0, 0);
            }

            // layer-2: per-lane partials then 16-lane reduce
            float ss[4] = {0.f,0.f,0.f,0.f};
            float sr[4] = {0.f,0.f,0.f,0.f};
            float sg[4] = {0.f,0.f,0.f,0.f};
            float sb[4] = {0.f,0.f,0.f,0.f};
            #pragma unroll
            for (int nt = 0; nt < 4; ++nt) {
                #pragma unroll
                for (int reg = 0; reg < 4; ++reg) {
                    const float hd = fmaxf(accd[nt][reg], 0.0f);
                    ss[reg] += hd * wd2v[nt];
                    const float hc = fmaxf(accc[nt][reg], 0.0f);
                    sr[reg] += hc * wc2r[nt];
                    sg[reg] += hc * wc2g[nt];
                    sb[reg] += hc * wc2b[nt];
                }
            }
            #pragma unroll
            for (int st = 1; st < 16; st <<= 1) {
                #pragma unroll
                for (int reg = 0; reg < 4; ++reg) {
                    ss[reg] += __shfl_xor(ss[reg], st, 64);
                    sr[reg] += __shfl_xor(sr[reg], st, 64);
                    sg[reg] += __shfl_xor(sg[reg], st, 64);
                    sb[reg] += __shfl_xor(sb[reg], st, 64);
                }
            }
            if (lane15 == 0) {
                const int base = wv*64 + mt*16 + laneg*4;  // D row = (lane>>4)*4 + reg
                #pragma unroll
                for (int reg = 0; reg < 4; ++reg) {
                    const int   row = base + reg;          // sample-in-ray
                    const float tr  = tnear + STEP * (float)row;
                    const bool  mr  = (tr < tmax) && hit;
                    float4 o;
                    o.x = mr ? (ss[reg] + bd2v) : 0.0f;    // masked sigma
                    o.y = sr[reg]; o.z = sg[reg]; o.w = sb[reg];  // rgb logits (pre-bc2)
                    samp[(size_t)ray*NSAMP + row] = o;
                }
            }
        }
    }
}

// ================= K2: per-ray compositing (sigmoid, alpha, scan, reduce) ====
__global__ __launch_bounds__(256) void nerf_comp(
    const float4* __restrict__ samp, const float* __restrict__ bc2,
    float* __restrict__ out)
{
    const float STEP = 0.0176f;
    const int b    = blockIdx.x;
    const int tid  = threadIdx.x;
    const int lane = tid & 63;
    const int wv   = tid >> 6;

    __shared__ float s_wtot[4];
    __shared__ float s_red[4][4];

    const float4 v = samp[(size_t)b*NSAMP + tid];
    const float sigma = v.x;                       // 0 for masked samples
    const float rr = 1.0f/(1.0f + expf(-(v.y + bc2[0])));
    const float rg = 1.0f/(1.0f + expf(-(v.z + bc2[1])));
    const float rb = 1.0f/(1.0f + expf(-(v.w + bc2[2])));

    const float alpha = 1.0f - expf(-fmaxf(sigma, 0.0f) * STEP);
    float p = 1.0f - alpha + 1e-10f;

    float scan = p;
    #pragma unroll
    for (int off = 1; off < 64; off <<= 1) {
        const float n = __shfl_up(scan, off, 64);
        if (lane >= off) scan *= n;
    }
    if (lane == 63) s_wtot[wv] = scan;
    __syncthreads();

    float pre = 1.0f;
    #pragma unroll
    for (int q = 0; q < 4; ++q) if (q < wv) pre *= s_wtot[q];
    float excl = __shfl_up(scan, 1, 64);
    if (lane == 0) excl = 1.0f;
    const float Texcl = pre * excl;

    const float w = alpha * Texcl;
    float sw  = w;
    float swr = w * rr, swg = w * rg, swb = w * rb;

    #pragma unroll
    for (int off = 32; off > 0; off >>= 1) {
        sw  += __shfl_down(sw,  off, 64);
        swr += __shfl_down(swr, off, 64);
        swg += __shfl_down(swg, off, 64);
        swb += __shfl_down(swb, off, 64);
    }
    if (lane == 0) {
        s_red[wv][0] = sw;  s_red[wv][1] = swr;
        s_red[wv][2] = swg; s_red[wv][3] = swb;
    }
    __syncthreads();
    if (tid == 0) {
        float W = 0.0f, R = 0.0f, Gc = 0.0f, Bc_ = 0.0f;
        #pragma unroll
        for (int q = 0; q < 4; ++q) {
            W  += s_red[q][0]; R  += s_red[q][1];
            Gc += s_red[q][2]; Bc_ += s_red[q][3];
        }
        const float bg = 1.0f - W;
        out[b*3+0] = R   + bg;
        out[b*3+1] = Gc  + bg;
        out[b*3+2] = Bc_ + bg;
    }
}

// ================= fallback single-kernel (round-9 structure) ================
template<bool USE_MFMA>
__global__ __launch_bounds__(256) __attribute__((amdgpu_waves_per_eu(2, 6)))
void nerf_fused(
    const float* __restrict__ rays_o, const float* __restrict__ rays_d,
    const float* __restrict__ G1, const float* __restrict__ Fg,
    const float* __restrict__ Wd1, const float* __restrict__ bd1,
    const float* __restrict__ Wd2, const float* __restrict__ bd2,
    const float* __restrict__ Wc1, const float* __restrict__ bc1,
    const float* __restrict__ Wc2, const float* __restrict__ bc2,
    const float* __restrict__ Ft,
    const f16* __restrict__ Bd, const f16* __restrict__ Bc,
    float* __restrict__ out)
{
    const float RADIUS = 1.3f;
    const float STEP = 0.0176f;

    const int b    = blockIdx.x;
    const int tid  = threadIdx.x;
    const int lane = tid & 63;
    const int wv   = tid >> 6;

    __shared__ __align__(16) f16 feats_lds[256][40];
    __shared__ float sig_lds[256];
    __shared__ f16   rgb_lds[256][4];
    __shared__ float s_wtot[4];
    __shared__ float s_red[4][4];

    const float ox = rays_o[b*3+0], oy = rays_o[b*3+1], oz = rays_o[b*3+2];
    const float rdx = rays_d[b*3+0], rdy = rays_d[b*3+1], rdz = rays_d[b*3+2];
    const float rn  = sqrtf(rdx*rdx + rdy*rdy + rdz*rdz);
    const float dxn = rdx/rn, dyn = rdy/rn, dzn = rdz/rn;

    float sd, inv, t1, t2, tmin, tmax;
    sd = (fabsf(dxn) < 1e-9f) ? 1e-9f : dxn; inv = 1.0f/sd;
    t1 = (-RADIUS - ox)*inv; t2 = (RADIUS - ox)*inv;
    tmin = fminf(t1,t2); tmax = fmaxf(t1,t2);
    sd = (fabsf(dyn) < 1e-9f) ? 1e-9f : dyn; inv = 1.0f/sd;
    t1 = (-RADIUS - oy)*inv; t2 = (RADIUS - oy)*inv;
    tmin = fmaxf(tmin, fminf(t1,t2)); tmax = fminf(tmax, fmaxf(t1,t2));
    sd = (fabsf(dzn) < 1e-9f) ? 1e-9f : dzn; inv = 1.0f/sd;
    t1 = (-RADIUS - oz)*inv; t2 = (RADIUS - oz)*inv;
    tmin = fmaxf(tmin, fminf(t1,t2)); tmax = fminf(tmax, fmaxf(t1,t2));

    const float tnear = fmaxf(tmin, 0.0f);
    const bool  hit   = tmax > tnear;
    const float t     = tnear + STEP * (float)tid;
    const bool  mask  = (t < tmax) && hit;

    const bool wave_active = __any(mask);

    float sigma = 0.0f, rr = 0.0f, rg = 0.0f, rb = 0.0f;

    float feats[32];
    if (wave_active) {
        const float invR = 1.0f / RADIUS;
        const float px = (ox + t*dxn) * invR;
        const float py = (oy + t*dyn) * invR;
        const float pz = (oz + t*dzn) * invR;

        float cox = fminf(fmaxf((px+1.0f)*0.5f*127.0f, 0.0f), 127.0f);
        float coy = fminf(fmaxf((py+1.0f)*0.5f*127.0f, 0.0f), 127.0f);
        float coz = fminf(fmaxf((pz+1.0f)*0.5f*127.0f, 0.0f), 127.0f);
        int x0 = (int)floorf(cox); float fx = cox - (float)x0; int x1 = min(x0+1, 127);
        int y0 = (int)floorf(coy); float fy = coy - (float)y0; int y1 = min(y0+1, 127);
        int z0 = (int)floorf(coz); float fz = coz - (float)z0; int z1 = min(z0+1, 127);

        {
            const float wx0 = 1.0f-fx, wx1 = fx;
            const float wy0 = 1.0f-fy, wy1 = fy;
            const float wz0 = 1.0f-fz, wz1 = fz;
            const float w000 = wx0*wy0*wz0, w100 = wx1*wy0*wz0;
            const float w010 = wx0*wy1*wz0, w110 = wx1*wy1*wz0;
            const float w001 = wx0*wy0*wz1, w101 = wx1*wy0*wz1;
            const float w011 = wx0*wy1*wz1, w111 = wx1*wy1*wz1;
            const int i000 = (z0*128 + y0)*128 + x0;
            const int dxo = x1 - x0;
            const int dyo = (y1 - y0)*128;
            const int dzo = (z1 - z0)*16384;
            const int i100 = i000 + dxo,       i010 = i000 + dyo;
            const int i110 = i000 + dyo + dxo, i001 = i000 + dzo;
            const int i101 = i000 + dzo + dxo, i011 = i000 + dzo + dyo;
            const int i111 = i000 + dzo + dyo + dxo;

            float g[3];
            #pragma unroll
            for (int c = 0; c < 3; ++c) {
                const float* gp = G1 + (size_t)c * 2097152;
                g[c] = w000*gp[i000] + w100*gp[i100] + w010*gp[i010] + w110*gp[i110]
                     + w001*gp[i001] + w101*gp[i101] + w011*gp[i011] + w111*gp[i111];
            }

            cox = fminf(fmaxf((g[0]+1.0f)*0.5f*31.0f, 0.0f), 31.0f);
            coy = fminf(fmaxf((g[1]+1.0f)*0.5f*31.0f, 0.0f), 31.0f);
            coz = fminf(fmaxf((g[2]+1.0f)*0.5f*31.0f, 0.0f), 31.0f);
            x0 = (int)floorf(cox); fx = cox - (float)x0; x1 = min(x0+1, 31);
            y0 = (int)floorf(coy); fy = coy - (float)y0; y1 = min(y0+1, 31);
            z0 = (int)floorf(coz); fz = coz - (float)z0; z1 = min(z0+1, 31);
        }

        #pragma unroll
        for (int c = 0; c < 32; ++c) feats[c] = 0.0f;
        {
            const float wx0 = 1.0f-fx, wx1 = fx;
            const float wy0 = 1.0f-fy, wy1 = fy;
            const float wz0 = 1.0f-fz, wz1 = fz;
            const int j000 = (z0*32 + y0)*32 + x0;
            const int dxo = x1 - x0;
            const int dyo = (y1 - y0)*32;
            const int dzo = (z1 - z0)*1024;

            const int   jidx[8] = { j000,           j000+dxo,
                                    j000+dyo,       j000+dyo+dxo,
                                    j000+dzo,       j000+dzo+dxo,
                                    j000+dzo+dyo,   j000+dzo+dyo+dxo };
            const float jwt[8]  = { wx0*wy0*wz0, wx1*wy0*wz0,
                                    wx0*wy1*wz0, wx1*wy1*wz0,
                                    wx0*wy0*wz1, wx1*wy0*wz1,
                                    wx0*wy1*wz1, wx1*wy1*wz1 };

            if (USE_MFMA) {
                #pragma unroll
                for (int corner = 0; corner < 8; ++corner) {
                    const float4* fp = (const float4*)(Ft + (size_t)jidx[corner] * 32);
                    const float w = jwt[corner];
                    #pragma unroll
                    for (int q = 0; q < 8; ++q) {
                        const float4 v = fp[q];
                        feats[4*q+0] += w * v.x;
                        feats[4*q+1] += w * v.y;
                        feats[4*q+2] += w * v.z;
                        feats[4*q+3] += w * v.w;
                    }
                }
            } else {
                #pragma unroll
                for (int corner = 0; corner < 8; ++corner) {
                    const float w = jwt[corner];
                    const int  j  = jidx[corner];
                    #pragma unroll
                    for (int c = 0; c < 32; ++c)
                        feats[c] += w * Fg[(size_t)c * 32768 + j];
                }
            }
        }
    }

    if (USE_MFMA) {
        if (wave_active) {
            #pragma unroll
            for (int gq = 0; gq < 4; ++gq) {
                f16x8 h;
                #pragma unroll
                for (int i = 0; i < 8; ++i) h[i] = (f16)feats[gq*8+i];
                *(f16x8*)&feats_lds[tid][gq*8] = h;
            }
        }
        __syncthreads();

        if (wave_active) {
            const int lane15 = lane & 15;
            const int laneg  = lane >> 4;

            float bias_d[4], bias_c[4], wd2v[4];
            float wc2r[4], wc2g[4], wc2b[4];
            #pragma unroll
            for (int nt = 0; nt < 4; ++nt) {
                const int j = nt*16 + lane15;
                bias_d[nt] = bd1[j];
                bias_c[nt] = bc1[j] + dxn*Wc1[32*64+j] + dyn*Wc1[33*64+j] + dzn*Wc1[34*64+j];
                wd2v[nt]   = Wd2[j];
                wc2r[nt]   = Wc2[j*3+0];
                wc2g[nt]   = Wc2[j*3+1];
                wc2b[nt]   = Wc2[j*3+2];
            }
            f16x8 bdf[4], bcf[4];
            #pragma unroll
            for (int nt = 0; nt < 4; ++nt) {
                bdf[nt] = *(const f16x8*)(Bd + ((size_t)(nt*64+lane))*8);
                bcf[nt] = *(const f16x8*)(Bc + ((size_t)(nt*64+lane))*8);
            }

            #pragma unroll
            for (int mt = 0; mt < 4; ++mt) {
                const int arow = wv*64 + mt*16 + lane15;
                const f16x8 af = *(const f16x8*)&feats_lds[arow][laneg*8];

                f32x4 accd[4], accc[4];
                #pragma unroll
                for (int nt = 0; nt < 4; ++nt) {
                    const float bdv = bias_d[nt], bcv = bias_c[nt];
                    accd[nt] = (f32x4){bdv, bdv, bdv, bdv};
                    accc[nt] = (f32x4){bcv, bcv, bcv, bcv};
                }
                #pragma unroll
                for (int nt = 0; nt < 4; ++nt) {
                    accd[nt] = __builtin_amdgcn_mfma_f32_16x16x32_f16(af, bdf[nt], accd[nt], 0, 0, 0);
                    accc[nt] = __builtin_amdgcn_mfma_f32_16x16x32_f16(af, bcf[nt], accc[nt], 0, 0, 0);
                }

                float ss[4] = {0.f,0.f,0.f,0.f};
                float sr[4] = {0.f,0.f,0.f,0.f};
                float sg[4] = {0.f,0.f,0.f,0.f};
                float sb[4] = {0.f,0.f,0.f,0.f};
                #pragma unroll
                for (int nt = 0; nt < 4; ++nt) {
                    #pragma unroll
                    for (int reg = 0; reg < 4; ++reg) {
                        const float hd = fmaxf(accd[nt][reg], 0.0f);
                        ss[reg] += hd * wd2v[nt];
                        const float hc = fmaxf(accc[nt][reg], 0.0f);
                        sr[reg] += hc * wc2r[nt];
                        sg[reg] += hc * wc2g[nt];
                        sb[reg] += hc * wc2b[nt];
                    }
                }
                #pragma unroll
                for (int st = 1; st < 16; st <<= 1) {
                    #pragma unroll
                    for (int reg = 0; reg < 4; ++reg) {
                        ss[reg] += __shfl_xor(ss[reg], st, 64);
                        sr[reg] += __shfl_xor(sr[reg], st, 64);
                        sg[reg] += __shfl_xor(sg[reg], st, 64);
                        sb[reg] += __shfl_xor(sb[reg], st, 64);
                    }
                }
                if (lane15 == 0) {
                    const int base = wv*64 + mt*16 + laneg*4;
                    #pragma unroll
                    for (int reg = 0; reg < 4; ++reg) {
                        sig_lds[base+reg]    = ss[reg];
                        rgb_lds[base+reg][0] = (f16)sr[reg];
                        rgb_lds[base+reg][1] = (f16)sg[reg];
                        rgb_lds[base+reg][2] = (f16)sb[reg];
                    }
                }
            }
        }
        __syncthreads();

        {
            const float sv  = sig_lds[tid];
            const float crv = (float)rgb_lds[tid][0] + bc2[0];
            const float cgv = (float)rgb_lds[tid][1] + bc2[1];
            const float cbv = (float)rgb_lds[tid][2] + bc2[2];
            sigma = mask ? (sv + bd2[0]) : 0.0f;
            rr = mask ? 1.0f/(1.0f + expf(-crv)) : 0.0f;
            rg = mask ? 1.0f/(1.0f + expf(-cgv)) : 0.0f;
            rb = mask ? 1.0f/(1.0f + expf(-cbv)) : 0.0f;
        }
    } else {
        if (wave_active) {
            float sg1 = bd2[0], cr = 0.0f, cg = 0.0f, cb = 0.0f;
            for (int j0 = 0; j0 < 64; j0 += 8) {
                float ad[8], ac[8];
                #pragma unroll
                for (int jj = 0; jj < 8; ++jj) {
                    ad[jj] = bd1[j0+jj];
                    ac[jj] = bc1[j0+jj] + dxn*Wc1[32*64 + j0 + jj]
                                        + dyn*Wc1[33*64 + j0 + jj]
                                        + dzn*Wc1[34*64 + j0 + jj];
                }
                #pragma unroll
                for (int k = 0; k < 32; ++k) {
                    const float fv = feats[k];
                    #pragma unroll
                    for (int jj = 0; jj < 8; ++jj) {
                        ad[jj] += fv * Wd1[k*64 + j0 + jj];
                        ac[jj] += fv * Wc1[k*64 + j0 + jj];
                    }
                }
                #pragma unroll
                for (int jj = 0; jj < 8; ++jj) {
                    sg1 += fmaxf(ad[jj], 0.0f) * Wd2[j0+jj];
                    const float hc = fmaxf(ac[jj], 0.0f);
                    cr += hc * Wc2[(j0+jj)*3 + 0];
                    cg += hc * Wc2[(j0+jj)*3 + 1];
                    cb += hc * Wc2[(j0+jj)*3 + 2];
                }
            }
            cr += bc2[0]; cg += bc2[1]; cb += bc2[2];
            sigma = mask ? sg1 : 0.0f;
            rr = mask ? 1.0f/(1.0f + expf(-cr)) : 0.0f;
            rg = mask ? 1.0f/(1.0f + expf(-cg)) : 0.0f;
            rb = mask ? 1.0f/(1.0f + expf(-cb)) : 0.0f;
        }
    }

    const float alpha = 1.0f - expf(-fmaxf(sigma, 0.0f) * STEP);
    float p = 1.0f - alpha + 1e-10f;

    float scan = p;
    #pragma unroll
    for (int off = 1; off < 64; off <<= 1) {
        const float n = __shfl_up(scan, off, 64);
        if (lane >= off) scan *= n;
    }
    if (lane == 63) s_wtot[wv] = scan;
    __syncthreads();

    float pre = 1.0f;
    #pragma unroll
    for (int q = 0; q < 4; ++q) if (q < wv) pre *= s_wtot[q];
    float excl = __shfl_up(scan, 1, 64);
    if (lane == 0) excl = 1.0f;
    const float Texcl = pre * excl;

    const float w = alpha * Texcl;
    float sw  = w;
    float swr = w * rr, swg = w * rg, swb = w * rb;

    #pragma unroll
    for (int off = 32; off > 0; off >>= 1) {
        sw  += __shfl_down(sw,  off, 64);
        swr += __shfl_down(swr, off, 64);
        swg += __shfl_down(swg, off, 64);
        swb += __shfl_down(swb, off, 64);
    }
    if (lane == 0) {
        s_red[wv][0] = sw;  s_red[wv][1] = swr;
        s_red[wv][2] = swg; s_red[wv][3] = swb;
    }
    __syncthreads();
    if (tid == 0) {
        float W = 0.0f, R = 0.0f, Gc = 0.0f, Bc2_ = 0.0f;
        #pragma unroll
        for (int q = 0; q < 4; ++q) {
            W  += s_red[q][0]; R  += s_red[q][1];
            Gc += s_red[q][2]; Bc2_ += s_red[q][3];
        }
        const float bg = 1.0f - W;
        out[b*3+0] = R  + bg;
        out[b*3+1] = Gc + bg;
        out[b*3+2] = Bc2_ + bg;
    }
}

extern "C" void kernel_launch(void* const* d_in, const int* in_sizes, int n_in,
                              void* d_out, int out_size, void* d_ws, size_t ws_size,
                              hipStream_t stream) {
    const float* rays_o = (const float*)d_in[0];
    const float* rays_d = (const float*)d_in[1];
    const float* G1     = (const float*)d_in[2];
    const float* Fg     = (const float*)d_in[3];
    const float* Wd1    = (const float*)d_in[4];
    const float* bd1    = (const float*)d_in[5];
    const float* Wd2    = (const float*)d_in[6];
    const float* bd2    = (const float*)d_in[7];
    const float* Wc1    = (const float*)d_in[8];
    const float* bc1    = (const float*)d_in[9];
    const float* Wc2    = (const float*)d_in[10];
    const float* bc2    = (const float*)d_in[11];
    float* out = (float*)d_out;

    const int B = in_sizes[0] / 3;   // 2048 rays
    const size_t ft_bytes   = (size_t)32768 * 32 * sizeof(float);    // 4 MB
    const size_t bf_bytes   = (size_t)4 * 64 * 8 * sizeof(f16);      // 4 KB each
    const size_t g1th_bytes = (size_t)2097152 * sizeof(f16x4);       // 16.8 MB
    const size_t samp_bytes = (size_t)B * NSAMP * sizeof(float4);    // 8.4 MB

    if (ws_size >= ft_bytes + 2*bf_bytes + g1th_bytes + samp_bytes) {
        float*  Ft   = (float*)d_ws;
        f16*    Bd   = (f16*)((char*)d_ws + ft_bytes);
        f16*    Bc   = (f16*)((char*)d_ws + ft_bytes + bf_bytes);
        f16x4*  G1t  = (f16x4*)((char*)d_ws + ft_bytes + 2*bf_bytes);
        float4* samp = (float4*)((char*)d_ws + ft_bytes + 2*bf_bytes + g1th_bytes);
        transpose_F<<<dim3(128), dim3(256), 0, stream>>>(Fg, Ft);
        transpose_G1h<<<dim3(8192), dim3(256), 0, stream>>>(G1, G1t);
        pack_bfrags<<<dim3(1), dim3(256), 0, stream>>>(Wd1, Wc1, Bd, Bc);
        nerf_gather<<<dim3(B), dim3(NSAMP), 0, stream>>>(
            rays_o, rays_d, G1t, Ft, bd1, Wd2, bd2, Wc1, bc1, Wc2, Bd, Bc, samp);
        nerf_comp<<<dim3(B), dim3(NSAMP), 0, stream>>>(samp, bc2, out);
    } else if (ws_size >= ft_bytes + 2*bf_bytes) {
        float* Ft = (float*)d_ws;
        f16*   Bd = (f16*)((char*)d_ws + ft_bytes);
        f16*   Bc = (f16*)((char*)d_ws + ft_bytes + bf_bytes);
        transpose_F<<<dim3(128), dim3(256), 0, stream>>>(Fg, Ft);
        pack_bfrags<<<dim3(1), dim3(256), 0, stream>>>(Wd1, Wc1, Bd, Bc);
        nerf_fused<true><<<dim3(B), dim3(NSAMP), 0, stream>>>(
            rays_o, rays_d, G1, Fg, Wd1, bd1, Wd2, bd2, Wc1, bc1, Wc2, bc2,
            Ft, Bd, Bc, out);
    } else {
        nerf_fused<false><<<dim3(B), dim3(NSAMP), 0, stream>>>(
            rays_o, rays_d, G1, Fg, Wd1, bd1, Wd2, bd2, Wc1, bc1, Wc2, bc2,
            Fg, (const f16*)d_ws, (const f16*)d_ws, out);
    }
}

// Round 14
// 142.006 us; speedup vs baseline: 1.0593x; 1.0593x over previous
//
#include <hip/hip_runtime.h>
#include <hip/hip_fp16.h>
#include <math.h>

#define NSAMP 256

typedef _Float16 f16;
typedef _Float16 f16x4 __attribute__((ext_vector_type(4)));
typedef _Float16 f16x8 __attribute__((ext_vector_type(8)));
typedef float    f32x4 __attribute__((ext_vector_type(4)));

// ---------- pre-pass 1: F [32ch][32768vox] -> Ft16 [32769vox][32] f16 ----------
// 64B/voxel; +1 pad row (zeros) so the x-pair read at the last voxel is in-bounds.
__global__ __launch_bounds__(256) void transpose_F16(
    const float* __restrict__ Fg, f16* __restrict__ Ft)
{
    const int j = blockIdx.x * 256 + threadIdx.x;   // voxel id 0..32767
    f16x8 o[4];
    #pragma unroll
    for (int q = 0; q < 4; ++q)
        #pragma unroll
        for (int i = 0; i < 8; ++i)
            o[q][i] = (f16)Fg[(size_t)(8*q+i)*32768 + j];
    f16* dst = Ft + (size_t)j * 32;
    #pragma unroll
    for (int q = 0; q < 4; ++q) *(f16x8*)(dst + q*8) = o[q];
    if (j == 32767) {   // zero the pad row
        f16x8 z = {};
        f16* pd = Ft + (size_t)32768 * 32;
        #pragma unroll
        for (int q = 0; q < 4; ++q) *(f16x8*)(pd + q*8) = z;
    }
}

// ---------- pre-pass 1b: G1 [3ch][128^3] -> G1p [128^3] f16x8 (16B) ----------
// Each entry holds channels of voxel v AND v+1 -> the main kernel's x-corner
// pair is ONE aligned 16B load. Hi half at x-edges has interpolation weight
// fx == 0 (clamped coord), so its garbage value never contributes.
__global__ __launch_bounds__(256) void transpose_G1p(
    const float* __restrict__ G1, f16x8* __restrict__ G1p)
{
    const int v  = blockIdx.x * 256 + threadIdx.x;   // 0..2097151
    const int vn = min(v + 1, 2097151);
    f16x8 o;
    o[0] = (f16)G1[v];
    o[1] = (f16)G1[2097152 + v];
    o[2] = (f16)G1[2*2097152 + v];
    o[3] = (f16)0.0f;
    o[4] = (f16)G1[vn];
    o[5] = (f16)G1[2097152 + vn];
    o[6] = (f16)G1[2*2097152 + vn];
    o[7] = (f16)0.0f;
    G1p[v] = o;
}

// ---------- pre-pass 2: pack layer-1 weights as MFMA B-fragments ----------
// B-frag lane layout for mfma_f32_16x16x32_f16: col j = lane&15,
// k = 8*(lane>>4) + i (i=0..7). Must match A-side LDS read order.
__global__ __launch_bounds__(256) void pack_bfrags(
    const float* __restrict__ Wd1, const float* __restrict__ Wc1,
    f16* __restrict__ Bd, f16* __restrict__ Bc)
{
    const int idx  = threadIdx.x;          // 0..255, single block
    const int nt   = idx >> 6;             // N-tile 0..3
    const int lane = idx & 63;
    const int j    = nt*16 + (lane & 15);
    const int k0   = (lane >> 4) * 8;
    f16x8 vd, vc;
    #pragma unroll
    for (int i = 0; i < 8; ++i) {
        vd[i] = (f16)Wd1[(k0+i)*64 + j];
        vc[i] = (f16)Wc1[(k0+i)*64 + j];
    }
    *(f16x8*)(Bd + ((size_t)(nt*64+lane))*8) = vd;
    *(f16x8*)(Bc + ((size_t)(nt*64+lane))*8) = vc;
}

// ================= main fused kernel =================
// Round-13: reverted the K1/K2 split (balancing was a null result -> the
// limiter is per-CU L1/TA request throughput on divergent gathers, which is
// wave-count-invariant). This round halves request count twice:
// G1 via 16B pair-entries (8 loads -> 4), F via f16 rows + x-pair lines
// (64 loads -> 32). All 16B aligned.
__global__ __launch_bounds__(256) __attribute__((amdgpu_waves_per_eu(2, 6)))
void nerf_fused_opt(
    const float* __restrict__ rays_o, const float* __restrict__ rays_d,
    const f16x8* __restrict__ G1p, const f16* __restrict__ Ft16,
    const float* __restrict__ bd1, const float* __restrict__ Wd2,
    const float* __restrict__ bd2,
    const float* __restrict__ Wc1, const float* __restrict__ bc1,
    const float* __restrict__ Wc2, const float* __restrict__ bc2,
    const f16* __restrict__ Bd, const f16* __restrict__ Bc,
    float* __restrict__ out)
{
    const float RADIUS = 1.3f;
    const float STEP = 0.0176f;

    const int b    = blockIdx.x;
    const int tid  = threadIdx.x;
    const int lane = tid & 63;
    const int wv   = tid >> 6;

    __shared__ __align__(16) f16 feats_lds[256][40];  // 80B rows (bank-spread)
    __shared__ float sig_lds[256];
    __shared__ f16   rgb_lds[256][4];
    __shared__ float s_wtot[4];
    __shared__ float s_red[4][4];

    // ---- ray setup ----
    const float ox = rays_o[b*3+0], oy = rays_o[b*3+1], oz = rays_o[b*3+2];
    const float rdx = rays_d[b*3+0], rdy = rays_d[b*3+1], rdz = rays_d[b*3+2];
    const float rn  = sqrtf(rdx*rdx + rdy*rdy + rdz*rdz);
    const float dxn = rdx/rn, dyn = rdy/rn, dzn = rdz/rn;

    // ---- cube intersection ----
    float sd, inv, t1, t2, tmin, tmax;
    sd = (fabsf(dxn) < 1e-9f) ? 1e-9f : dxn; inv = 1.0f/sd;
    t1 = (-RADIUS - ox)*inv; t2 = (RADIUS - ox)*inv;
    tmin = fminf(t1,t2); tmax = fmaxf(t1,t2);
    sd = (fabsf(dyn) < 1e-9f) ? 1e-9f : dyn; inv = 1.0f/sd;
    t1 = (-RADIUS - oy)*inv; t2 = (RADIUS - oy)*inv;
    tmin = fmaxf(tmin, fminf(t1,t2)); tmax = fminf(tmax, fmaxf(t1,t2));
    sd = (fabsf(dzn) < 1e-9f) ? 1e-9f : dzn; inv = 1.0f/sd;
    t1 = (-RADIUS - oz)*inv; t2 = (RADIUS - oz)*inv;
    tmin = fmaxf(tmin, fminf(t1,t2)); tmax = fminf(tmax, fmaxf(t1,t2));

    const float tnear = fmaxf(tmin, 0.0f);
    const bool  hit   = tmax > tnear;
    const float t     = tnear + STEP * (float)tid;
    const bool  mask  = (t < tmax) && hit;

    const bool wave_active = __any(mask);

    float sigma = 0.0f, rr = 0.0f, rg = 0.0f, rb = 0.0f;

    // =========================== gather phase ===========================
    float feats[32];
    if (wave_active) {
        const float invR = 1.0f / RADIUS;
        const float px = (ox + t*dxn) * invR;
        const float py = (oy + t*dyn) * invR;
        const float pz = (oz + t*dzn) * invR;

        float cox = fminf(fmaxf((px+1.0f)*0.5f*127.0f, 0.0f), 127.0f);
        float coy = fminf(fmaxf((py+1.0f)*0.5f*127.0f, 0.0f), 127.0f);
        float coz = fminf(fmaxf((pz+1.0f)*0.5f*127.0f, 0.0f), 127.0f);
        int x0 = (int)floorf(cox); float fx = cox - (float)x0;
        int y0 = (int)floorf(coy); float fy = coy - (float)y0; int y1 = min(y0+1, 127);
        int z0 = (int)floorf(coz); float fz = coz - (float)z0; int z1 = min(z0+1, 127);

        {
            const float wx0 = 1.0f-fx, wx1 = fx;   // at x0==127, fx==0 -> hi half unused
            const float wy0 = 1.0f-fy, wy1 = fy;
            const float wz0 = 1.0f-fz, wz1 = fz;
            const int i000 = (z0*128 + y0)*128 + x0;
            const int dyo = (y1 - y0)*128;
            const int dzo = (z1 - z0)*16384;

            const f16x8 p00 = G1p[i000];
            const f16x8 p10 = G1p[i000 + dyo];
            const f16x8 p01 = G1p[i000 + dzo];
            const f16x8 p11 = G1p[i000 + dyo + dzo];

            const float a00 = wy0*wz0, a10 = wy1*wz0, a01 = wy0*wz1, a11 = wy1*wz1;

            float g[3];
            #pragma unroll
            for (int c = 0; c < 3; ++c) {
                g[c] = a00*(wx0*(float)p00[c] + wx1*(float)p00[4+c])
                     + a10*(wx0*(float)p10[c] + wx1*(float)p10[4+c])
                     + a01*(wx0*(float)p01[c] + wx1*(float)p01[4+c])
                     + a11*(wx0*(float)p11[c] + wx1*(float)p11[4+c]);
            }

            cox = fminf(fmaxf((g[0]+1.0f)*0.5f*31.0f, 0.0f), 31.0f);
            coy = fminf(fmaxf((g[1]+1.0f)*0.5f*31.0f, 0.0f), 31.0f);
            coz = fminf(fmaxf((g[2]+1.0f)*0.5f*31.0f, 0.0f), 31.0f);
            x0 = (int)floorf(cox); fx = cox - (float)x0;
            y0 = (int)floorf(coy); fy = coy - (float)y0; y1 = min(y0+1, 31);
            z0 = (int)floorf(coz); fz = coz - (float)z0; z1 = min(z0+1, 31);
        }

        // ---- trilinear F: 4 corner-pairs, each = one 128B line (8x16B) ----
        #pragma unroll
        for (int c = 0; c < 32; ++c) feats[c] = 0.0f;
        {
            const float wx0 = 1.0f-fx, wx1 = fx;   // at x0==31, fx==0 -> pad row unused
            const float wy0 = 1.0f-fy, wy1 = fy;
            const float wz0 = 1.0f-fz, wz1 = fz;
            const int j000 = (z0*32 + y0)*32 + x0;
            const int dyo = (y1 - y0)*32;
            const int dzo = (z1 - z0)*1024;

            const int   jp[4] = { j000, j000+dyo, j000+dzo, j000+dyo+dzo };
            const float ap[4] = { wy0*wz0, wy1*wz0, wy0*wz1, wy1*wz1 };

            #pragma unroll
            for (int p = 0; p < 4; ++p) {
                const f16* base = Ft16 + (size_t)jp[p] * 32;
                const float aw = ap[p]*wx0, bw = ap[p]*wx1;
                f16x8 lo[4], hi[4];
                #pragma unroll
                for (int q = 0; q < 4; ++q) lo[q] = *(const f16x8*)(base + q*8);
                #pragma unroll
                for (int q = 0; q < 4; ++q) hi[q] = *(const f16x8*)(base + 32 + q*8);
                #pragma unroll
                for (int q = 0; q < 4; ++q)
                    #pragma unroll
                    for (int i = 0; i < 8; ++i)
                        feats[8*q+i] += aw*(float)lo[q][i] + bw*(float)hi[q][i];
            }
        }
    }

    // ---- stage feats to LDS as f16 ----
    if (wave_active) {
        #pragma unroll
        for (int gq = 0; gq < 4; ++gq) {
            f16x8 h;
            #pragma unroll
            for (int i = 0; i < 8; ++i) h[i] = (f16)feats[gq*8+i];
            *(f16x8*)&feats_lds[tid][gq*8] = h;
        }
    }
    __syncthreads();

    // ---- MFMA phase: each wave computes its own 64 samples ----
    if (wave_active) {
        const int lane15 = lane & 15;
        const int laneg  = lane >> 4;

        float bias_d[4], bias_c[4], wd2v[4];
        float wc2r[4], wc2g[4], wc2b[4];
        #pragma unroll
        for (int nt = 0; nt < 4; ++nt) {
            const int j = nt*16 + lane15;
            bias_d[nt] = bd1[j];
            bias_c[nt] = bc1[j] + dxn*Wc1[32*64+j] + dyn*Wc1[33*64+j] + dzn*Wc1[34*64+j];
            wd2v[nt]   = Wd2[j];
            wc2r[nt]   = Wc2[j*3+0];
            wc2g[nt]   = Wc2[j*3+1];
            wc2b[nt]   = Wc2[j*3+2];
        }
        f16x8 bdf[4], bcf[4];
        #pragma unroll
        for (int nt = 0; nt < 4; ++nt) {
            bdf[nt] = *(const f16x8*)(Bd + ((size_t)(nt*64+lane))*8);
            bcf[nt] = *(const f16x8*)(Bc + ((size_t)(nt*64+lane))*8);
        }

        #pragma unroll
        for (int mt = 0; mt < 4; ++mt) {
            const int arow = wv*64 + mt*16 + lane15;
            const f16x8 af = *(const f16x8*)&feats_lds[arow][laneg*8];

            f32x4 accd[4], accc[4];
            #pragma unroll
            for (int nt = 0; nt < 4; ++nt) {
                const float bdv = bias_d[nt], bcv = bias_c[nt];
                accd[nt] = (f32x4){bdv, bdv, bdv, bdv};
                accc[nt] = (f32x4){bcv, bcv, bcv, bcv};
            }
            #pragma unroll
            for (int nt = 0; nt < 4; ++nt) {
                accd[nt] = __builtin_amdgcn_mfma_f32_16x16x32_f16(af, bdf[nt], accd[nt], 0, 0, 0);
                accc[nt] = __builtin_amdgcn_mfma_f32_16x16x32_f16(af, bcf[nt], accc[nt], 0, 0, 0);
            }

            // layer-2: per-lane partials then 16-lane reduce
            float ss[4] = {0.f,0.f,0.f,0.f};
            float sr[4] = {0.f,0.f,0.f,0.f};
            float sg[4] = {0.f,0.f,0.f,0.f};
            float sb[4] = {0.f,0.f,0.f,0.f};
            #pragma unroll
            for (int nt = 0; nt < 4; ++nt) {
                #pragma unroll
                for (int reg = 0; reg < 4; ++reg) {
                    const float hd = fmaxf(accd[nt][reg], 0.0f);
                    ss[reg] += hd * wd2v[nt];
                    const float hc = fmaxf(accc[nt][reg], 0.0f);
                    sr[reg] += hc * wc2r[nt];
                    sg[reg] += hc * wc2g[nt];
                    sb[reg] += hc * wc2b[nt];
                }
            }
            #pragma unroll
            for (int st = 1; st < 16; st <<= 1) {
                #pragma unroll
                for (int reg = 0; reg < 4; ++reg) {
                    ss[reg] += __shfl_xor(ss[reg], st, 64);
                    sr[reg] += __shfl_xor(sr[reg], st, 64);
                    sg[reg] += __shfl_xor(sg[reg], st, 64);
                    sb[reg] += __shfl_xor(sb[reg], st, 64);
                }
            }
            if (lane15 == 0) {
                const int base = wv*64 + mt*16 + laneg*4;  // D row = (lane>>4)*4 + reg
                #pragma unroll
                for (int reg = 0; reg < 4; ++reg) {
                    sig_lds[base+reg]    = ss[reg];
                    rgb_lds[base+reg][0] = (f16)sr[reg];
                    rgb_lds[base+reg][1] = (f16)sg[reg];
                    rgb_lds[base+reg][2] = (f16)sb[reg];
                }
            }
        }
    }
    __syncthreads();

    // ---- owner pick-up ----
    {
        const float sv  = sig_lds[tid];
        const float crv = (float)rgb_lds[tid][0] + bc2[0];
        const float cgv = (float)rgb_lds[tid][1] + bc2[1];
        const float cbv = (float)rgb_lds[tid][2] + bc2[2];
        sigma = mask ? (sv + bd2[0]) : 0.0f;
        rr = mask ? 1.0f/(1.0f + expf(-crv)) : 0.0f;
        rg = mask ? 1.0f/(1.0f + expf(-cgv)) : 0.0f;
        rb = mask ? 1.0f/(1.0f + expf(-cbv)) : 0.0f;
    }

    // ---- alpha, exclusive product scan (T_excl), weights ----
    const float alpha = 1.0f - expf(-fmaxf(sigma, 0.0f) * STEP);
    float p = 1.0f - alpha + 1e-10f;

    float scan = p;
    #pragma unroll
    for (int off = 1; off < 64; off <<= 1) {
        const float n = __shfl_up(scan, off, 64);
        if (lane >= off) scan *= n;
    }
    if (lane == 63) s_wtot[wv] = scan;
    __syncthreads();

    float pre = 1.0f;
    #pragma unroll
    for (int q = 0; q < 4; ++q) if (q < wv) pre *= s_wtot[q];
    float excl = __shfl_up(scan, 1, 64);
    if (lane == 0) excl = 1.0f;
    const float Texcl = pre * excl;

    const float w = alpha * Texcl;
    float sw  = w;
    float swr = w * rr, swg = w * rg, swb = w * rb;

    // ---- block reduction ----
    #pragma unroll
    for (int off = 32; off > 0; off >>= 1) {
        sw  += __shfl_down(sw,  off, 64);
        swr += __shfl_down(swr, off, 64);
        swg += __shfl_down(swg, off, 64);
        swb += __shfl_down(swb, off, 64);
    }
    if (lane == 0) {
        s_red[wv][0] = sw;  s_red[wv][1] = swr;
        s_red[wv][2] = swg; s_red[wv][3] = swb;
    }
    __syncthreads();
    if (tid == 0) {
        float W = 0.0f, R = 0.0f, Gc = 0.0f, Bc_ = 0.0f;
        #pragma unroll
        for (int q = 0; q < 4; ++q) {
            W  += s_red[q][0]; R  += s_red[q][1];
            Gc += s_red[q][2]; Bc_ += s_red[q][3];
        }
        const float bg = 1.0f - W;
        out[b*3+0] = R   + bg;
        out[b*3+1] = Gc  + bg;
        out[b*3+2] = Bc_ + bg;
    }
}

// ================= fallback: fp32 per-thread everything (no workspace) =======
__global__ __launch_bounds__(256) __attribute__((amdgpu_waves_per_eu(2, 6)))
void nerf_fused_naive(
    const float* __restrict__ rays_o, const float* __restrict__ rays_d,
    const float* __restrict__ G1, const float* __restrict__ Fg,
    const float* __restrict__ Wd1, const float* __restrict__ bd1,
    const float* __restrict__ Wd2, const float* __restrict__ bd2,
    const float* __restrict__ Wc1, const float* __restrict__ bc1,
    const float* __restrict__ Wc2, const float* __restrict__ bc2,
    float* __restrict__ out)
{
    const float RADIUS = 1.3f;
    const float STEP = 0.0176f;

    const int b    = blockIdx.x;
    const int tid  = threadIdx.x;
    const int lane = tid & 63;
    const int wv   = tid >> 6;

    __shared__ float s_wtot[4];
    __shared__ float s_red[4][4];

    const float ox = rays_o[b*3+0], oy = rays_o[b*3+1], oz = rays_o[b*3+2];
    const float rdx = rays_d[b*3+0], rdy = rays_d[b*3+1], rdz = rays_d[b*3+2];
    const float rn  = sqrtf(rdx*rdx + rdy*rdy + rdz*rdz);
    const float dxn = rdx/rn, dyn = rdy/rn, dzn = rdz/rn;

    float sd, inv, t1, t2, tmin, tmax;
    sd = (fabsf(dxn) < 1e-9f) ? 1e-9f : dxn; inv = 1.0f/sd;
    t1 = (-RADIUS - ox)*inv; t2 = (RADIUS - ox)*inv;
    tmin = fminf(t1,t2); tmax = fmaxf(t1,t2);
    sd = (fabsf(dyn) < 1e-9f) ? 1e-9f : dyn; inv = 1.0f/sd;
    t1 = (-RADIUS - oy)*inv; t2 = (RADIUS - oy)*inv;
    tmin = fmaxf(tmin, fminf(t1,t2)); tmax = fminf(tmax, fmaxf(t1,t2));
    sd = (fabsf(dzn) < 1e-9f) ? 1e-9f : dzn; inv = 1.0f/sd;
    t1 = (-RADIUS - oz)*inv; t2 = (RADIUS - oz)*inv;
    tmin = fmaxf(tmin, fminf(t1,t2)); tmax = fminf(tmax, fmaxf(t1,t2));

    const float tnear = fmaxf(tmin, 0.0f);
    const bool  hit   = tmax > tnear;
    const float t     = tnear + STEP * (float)tid;
    const bool  mask  = (t < tmax) && hit;

    float sigma = 0.0f, rr = 0.0f, rg = 0.0f, rb = 0.0f;

    if (__any(mask)) {
        const float invR = 1.0f / RADIUS;
        const float px = (ox + t*dxn) * invR;
        const float py = (oy + t*dyn) * invR;
        const float pz = (oz + t*dzn) * invR;

        float cox = fminf(fmaxf((px+1.0f)*0.5f*127.0f, 0.0f), 127.0f);
        float coy = fminf(fmaxf((py+1.0f)*0.5f*127.0f, 0.0f), 127.0f);
        float coz = fminf(fmaxf((pz+1.0f)*0.5f*127.0f, 0.0f), 127.0f);
        int x0 = (int)floorf(cox); float fx = cox - (float)x0; int x1 = min(x0+1, 127);
        int y0 = (int)floorf(coy); float fy = coy - (float)y0; int y1 = min(y0+1, 127);
        int z0 = (int)floorf(coz); float fz = coz - (float)z0; int z1 = min(z0+1, 127);

        float feats[32];
        {
            const float wx0 = 1.0f-fx, wx1 = fx;
            const float wy0 = 1.0f-fy, wy1 = fy;
            const float wz0 = 1.0f-fz, wz1 = fz;
            const float w000 = wx0*wy0*wz0, w100 = wx1*wy0*wz0;
            const float w010 = wx0*wy1*wz0, w110 = wx1*wy1*wz0;
            const float w001 = wx0*wy0*wz1, w101 = wx1*wy0*wz1;
            const float w011 = wx0*wy1*wz1, w111 = wx1*wy1*wz1;
            const int i000 = (z0*128 + y0)*128 + x0;
            const int dxo = x1 - x0;
            const int dyo = (y1 - y0)*128;
            const int dzo = (z1 - z0)*16384;
            const int i100 = i000 + dxo,       i010 = i000 + dyo;
            const int i110 = i000 + dyo + dxo, i001 = i000 + dzo;
            const int i101 = i000 + dzo + dxo, i011 = i000 + dzo + dyo;
            const int i111 = i000 + dzo + dyo + dxo;

            float g[3];
            #pragma unroll
            for (int c = 0; c < 3; ++c) {
                const float* gp = G1 + (size_t)c * 2097152;
                g[c] = w000*gp[i000] + w100*gp[i100] + w010*gp[i010] + w110*gp[i110]
                     + w001*gp[i001] + w101*gp[i101] + w011*gp[i011] + w111*gp[i111];
            }

            cox = fminf(fmaxf((g[0]+1.0f)*0.5f*31.0f, 0.0f), 31.0f);
            coy = fminf(fmaxf((g[1]+1.0f)*0.5f*31.0f, 0.0f), 31.0f);
            coz = fminf(fmaxf((g[2]+1.0f)*0.5f*31.0f, 0.0f), 31.0f);
            x0 = (int)floorf(cox); fx = cox - (float)x0; x1 = min(x0+1, 31);
            y0 = (int)floorf(coy); fy = coy - (float)y0; y1 = min(y0+1, 31);
            z0 = (int)floorf(coz); fz = coz - (float)z0; z1 = min(z0+1, 31);

            const float vx0 = 1.0f-fx, vx1 = fx;
            const float vy0 = 1.0f-fy, vy1 = fy;
            const float vz0 = 1.0f-fz, vz1 = fz;
            const float u000 = vx0*vy0*vz0, u100 = vx1*vy0*vz0;
            const float u010 = vx0*vy1*vz0, u110 = vx1*vy1*vz0;
            const float u001 = vx0*vy0*vz1, u101 = vx1*vy0*vz1;
            const float u011 = vx0*vy1*vz1, u111 = vx1*vy1*vz1;
            const int j000 = (z0*32 + y0)*32 + x0;
            const int exo = x1 - x0;
            const int eyo = (y1 - y0)*32;
            const int ezo = (z1 - z0)*1024;
            const int j100 = j000 + exo,       j010 = j000 + eyo;
            const int j110 = j000 + eyo + exo, j001 = j000 + ezo;
            const int j101 = j000 + ezo + exo, j011 = j000 + ezo + eyo;
            const int j111 = j000 + ezo + eyo + exo;

            #pragma unroll
            for (int c = 0; c < 32; ++c) {
                const float* fp = Fg + (size_t)c * 32768;
                feats[c] = u000*fp[j000] + u100*fp[j100] + u010*fp[j010] + u110*fp[j110]
                         + u001*fp[j001] + u101*fp[j101] + u011*fp[j011] + u111*fp[j111];
            }
        }

        float sg1 = bd2[0], cr = 0.0f, cg = 0.0f, cb = 0.0f;
        for (int j0 = 0; j0 < 64; j0 += 8) {
            float ad[8], ac[8];
            #pragma unroll
            for (int jj = 0; jj < 8; ++jj) {
                ad[jj] = bd1[j0+jj];
                ac[jj] = bc1[j0+jj] + dxn*Wc1[32*64 + j0 + jj]
                                    + dyn*Wc1[33*64 + j0 + jj]
                                    + dzn*Wc1[34*64 + j0 + jj];
            }
            #pragma unroll
            for (int k = 0; k < 32; ++k) {
                const float fv = feats[k];
                #pragma unroll
                for (int jj = 0; jj < 8; ++jj) {
                    ad[jj] += fv * Wd1[k*64 + j0 + jj];
                    ac[jj] += fv * Wc1[k*64 + j0 + jj];
                }
            }
            #pragma unroll
            for (int jj = 0; jj < 8; ++jj) {
                sg1 += fmaxf(ad[jj], 0.0f) * Wd2[j0+jj];
                const float hc = fmaxf(ac[jj], 0.0f);
                cr += hc * Wc2[(j0+jj)*3 + 0];
                cg += hc * Wc2[(j0+jj)*3 + 1];
                cb += hc * Wc2[(j0+jj)*3 + 2];
            }
        }
        cr += bc2[0]; cg += bc2[1]; cb += bc2[2];
        sigma = mask ? sg1 : 0.0f;
        rr = mask ? 1.0f/(1.0f + expf(-cr)) : 0.0f;
        rg = mask ? 1.0f/(1.0f + expf(-cg)) : 0.0f;
        rb = mask ? 1.0f/(1.0f + expf(-cb)) : 0.0f;
    }

    const float alpha = 1.0f - expf(-fmaxf(sigma, 0.0f) * STEP);
    float p = 1.0f - alpha + 1e-10f;

    float scan = p;
    #pragma unroll
    for (int off = 1; off < 64; off <<= 1) {
        const float n = __shfl_up(scan, off, 64);
        if (lane >= off) scan *= n;
    }
    if (lane == 63) s_wtot[wv] = scan;
    __syncthreads();

    float pre = 1.0f;
    #pragma unroll
    for (int q = 0; q < 4; ++q) if (q < wv) pre *= s_wtot[q];
    float excl = __shfl_up(scan, 1, 64);
    if (lane == 0) excl = 1.0f;
    const float Texcl = pre * excl;

    const float w = alpha * Texcl;
    float sw  = w;
    float swr = w * rr, swg = w * rg, swb = w * rb;

    #pragma unroll
    for (int off = 32; off > 0; off >>= 1) {
        sw  += __shfl_down(sw,  off, 64);
        swr += __shfl_down(swr, off, 64);
        swg += __shfl_down(swg, off, 64);
        swb += __shfl_down(swb, off, 64);
    }
    if (lane == 0) {
        s_red[wv][0] = sw;  s_red[wv][1] = swr;
        s_red[wv][2] = swg; s_red[wv][3] = swb;
    }
    __syncthreads();
    if (tid == 0) {
        float W = 0.0f, R = 0.0f, Gc = 0.0f, Bc_ = 0.0f;
        #pragma unroll
        for (int q = 0; q < 4; ++q) {
            W  += s_red[q][0]; R  += s_red[q][1];
            Gc += s_red[q][2]; Bc_ += s_red[q][3];
        }
        const float bg = 1.0f - W;
        out[b*3+0] = R   + bg;
        out[b*3+1] = Gc  + bg;
        out[b*3+2] = Bc_ + bg;
    }
}

extern "C" void kernel_launch(void* const* d_in, const int* in_sizes, int n_in,
                              void* d_out, int out_size, void* d_ws, size_t ws_size,
                              hipStream_t stream) {
    const float* rays_o = (const float*)d_in[0];
    const float* rays_d = (const float*)d_in[1];
    const float* G1     = (const float*)d_in[2];
    const float* Fg     = (const float*)d_in[3];
    const float* Wd1    = (const float*)d_in[4];
    const float* bd1    = (const float*)d_in[5];
    const float* Wd2    = (const float*)d_in[6];
    const float* bd2    = (const float*)d_in[7];
    const float* Wc1    = (const float*)d_in[8];
    const float* bc1    = (const float*)d_in[9];
    const float* Wc2    = (const float*)d_in[10];
    const float* bc2    = (const float*)d_in[11];
    float* out = (float*)d_out;

    const int B = in_sizes[0] / 3;   // 2048 rays
    const size_t ft16_bytes = (size_t)32769 * 32 * sizeof(f16);    // ~2.1 MB (incl pad)
    const size_t g1p_bytes  = (size_t)2097152 * sizeof(f16x8);     // 33.55 MB
    const size_t bf_bytes   = (size_t)4 * 64 * 8 * sizeof(f16);    // 4 KB each

    if (ws_size >= ft16_bytes + g1p_bytes + 2*bf_bytes) {
        f16*   Ft16 = (f16*)d_ws;
        f16x8* G1p  = (f16x8*)((char*)d_ws + ft16_bytes);
        f16*   Bd   = (f16*)((char*)d_ws + ft16_bytes + g1p_bytes);
        f16*   Bc   = (f16*)((char*)d_ws + ft16_bytes + g1p_bytes + bf_bytes);
        transpose_F16<<<dim3(128), dim3(256), 0, stream>>>(Fg, Ft16);
        transpose_G1p<<<dim3(8192), dim3(256), 0, stream>>>(G1, G1p);
        pack_bfrags<<<dim3(1), dim3(256), 0, stream>>>(Wd1, Wc1, Bd, Bc);
        nerf_fused_opt<<<dim3(B), dim3(NSAMP), 0, stream>>>(
            rays_o, rays_d, G1p, Ft16, bd1, Wd2, bd2, Wc1, bc1, Wc2, bc2,
            Bd, Bc, out);
    } else {
        nerf_fused_naive<<<dim3(B), dim3(NSAMP), 0, stream>>>(
            rays_o, rays_d, G1, Fg, Wd1, bd1, Wd2, bd2, Wc1, bc1, Wc2, bc2, out);
    }
}

// Round 15
// 132.965 us; speedup vs baseline: 1.1314x; 1.0680x over previous
//
#include <hip/hip_runtime.h>
#include <hip/hip_fp16.h>
#include <math.h>

#define NSAMP 256

typedef _Float16 f16;
typedef _Float16 f16x2 __attribute__((ext_vector_type(2)));
typedef _Float16 f16x4 __attribute__((ext_vector_type(4)));
typedef _Float16 f16x8 __attribute__((ext_vector_type(8)));
typedef float    f32x4 __attribute__((ext_vector_type(4)));

// ---------- pre-pass 1: F [32ch][32768vox] -> Ft16 [32769vox][32] f16 ----------
__global__ __launch_bounds__(256) void transpose_F16(
    const float* __restrict__ Fg, f16* __restrict__ Ft)
{
    const int j = blockIdx.x * 256 + threadIdx.x;   // voxel id 0..32767
    f16x8 o[4];
    #pragma unroll
    for (int q = 0; q < 4; ++q)
        #pragma unroll
        for (int i = 0; i < 8; ++i)
            o[q][i] = (f16)Fg[(size_t)(8*q+i)*32768 + j];
    f16* dst = Ft + (size_t)j * 32;
    #pragma unroll
    for (int q = 0; q < 4; ++q) *(f16x8*)(dst + q*8) = o[q];
    if (j == 32767) {   // zero the pad row
        f16x8 z = {};
        f16* pd = Ft + (size_t)32768 * 32;
        #pragma unroll
        for (int q = 0; q < 4; ++q) *(f16x8*)(pd + q*8) = z;
    }
}

// ---------- pre-pass 1b: G1 [3ch][128^3] -> G1h [128^3] f16x4 (8B) ----------
// r15: back to 8B entries (r14 showed 16B pairing bought ~nothing in the main
// kernel; halving this pre-pass's write traffic saves ~5us of timed work).
__global__ __launch_bounds__(256) void transpose_G1h(
    const float* __restrict__ G1, f16x4* __restrict__ G1h)
{
    const int v = blockIdx.x * 256 + threadIdx.x;   // 0..2097151
    f16x4 o;
    o[0] = (f16)G1[v];
    o[1] = (f16)G1[2097152 + v];
    o[2] = (f16)G1[2*2097152 + v];
    o[3] = (f16)0.0f;
    G1h[v] = o;
}

// ---------- pre-pass 2: pack layer-1 weights as MFMA B-fragments ----------
__global__ __launch_bounds__(256) void pack_bfrags(
    const float* __restrict__ Wd1, const float* __restrict__ Wc1,
    f16* __restrict__ Bd, f16* __restrict__ Bc)
{
    const int idx  = threadIdx.x;          // 0..255, single block
    const int nt   = idx >> 6;             // N-tile 0..3
    const int lane = idx & 63;
    const int j    = nt*16 + (lane & 15);
    const int k0   = (lane >> 4) * 8;
    f16x8 vd, vc;
    #pragma unroll
    for (int i = 0; i < 8; ++i) {
        vd[i] = (f16)Wd1[(k0+i)*64 + j];
        vc[i] = (f16)Wc1[(k0+i)*64 + j];
    }
    *(f16x8*)(Bd + ((size_t)(nt*64+lane))*8) = vd;
    *(f16x8*)(Bc + ((size_t)(nt*64+lane))*8) = vc;
}

__device__ inline f16x2 shfl_xor_h2(f16x2 v, int m) {
    union { f16x2 h; int i; } u;
    u.h = v;
    u.i = __shfl_xor(u.i, m, 64);
    return u.h;
}

// ================= main fused kernel =================
// Round-15: (1) F-accumulate in packed f16 (v_pk_fma_f16) — cuts the largest
// VALU block ~5x; (2) layer-2 shuffle reduce packed f16x2 — halves ds-ops;
// (3) block-wide barriers around the MFMA phase REMOVED (feats/sig/rgb LDS
// rows are wave-private; same-wave DS ops are in-order) so waves de-align
// and overlap gather latency with other waves' compute.
__global__ __launch_bounds__(256) __attribute__((amdgpu_waves_per_eu(2, 6)))
void nerf_fused_opt(
    const float* __restrict__ rays_o, const float* __restrict__ rays_d,
    const f16x4* __restrict__ G1h, const f16* __restrict__ Ft16,
    const float* __restrict__ bd1, const float* __restrict__ Wd2,
    const float* __restrict__ bd2,
    const float* __restrict__ Wc1, const float* __restrict__ bc1,
    const float* __restrict__ Wc2, const float* __restrict__ bc2,
    const f16* __restrict__ Bd, const f16* __restrict__ Bc,
    float* __restrict__ out)
{
    const float RADIUS = 1.3f;
    const float STEP = 0.0176f;

    const int b    = blockIdx.x;
    const int tid  = threadIdx.x;
    const int lane = tid & 63;
    const int wv   = tid >> 6;

    __shared__ __align__(16) f16 feats_lds[256][40];  // 80B rows (bank-spread)
    __shared__ float sig_lds[256];
    __shared__ f16   rgb_lds[256][4];
    __shared__ float s_wtot[4];
    __shared__ float s_red[4][4];

    // ---- ray setup ----
    const float ox = rays_o[b*3+0], oy = rays_o[b*3+1], oz = rays_o[b*3+2];
    const float rdx = rays_d[b*3+0], rdy = rays_d[b*3+1], rdz = rays_d[b*3+2];
    const float rn  = sqrtf(rdx*rdx + rdy*rdy + rdz*rdz);
    const float dxn = rdx/rn, dyn = rdy/rn, dzn = rdz/rn;

    // ---- cube intersection ----
    float sd, inv, t1, t2, tmin, tmax;
    sd = (fabsf(dxn) < 1e-9f) ? 1e-9f : dxn; inv = 1.0f/sd;
    t1 = (-RADIUS - ox)*inv; t2 = (RADIUS - ox)*inv;
    tmin = fminf(t1,t2); tmax = fmaxf(t1,t2);
    sd = (fabsf(dyn) < 1e-9f) ? 1e-9f : dyn; inv = 1.0f/sd;
    t1 = (-RADIUS - oy)*inv; t2 = (RADIUS - oy)*inv;
    tmin = fmaxf(tmin, fminf(t1,t2)); tmax = fminf(tmax, fmaxf(t1,t2));
    sd = (fabsf(dzn) < 1e-9f) ? 1e-9f : dzn; inv = 1.0f/sd;
    t1 = (-RADIUS - oz)*inv; t2 = (RADIUS - oz)*inv;
    tmin = fmaxf(tmin, fminf(t1,t2)); tmax = fminf(tmax, fmaxf(t1,t2));

    const float tnear = fmaxf(tmin, 0.0f);
    const bool  hit   = tmax > tnear;
    const float t     = tnear + STEP * (float)tid;
    const bool  mask  = (t < tmax) && hit;

    const bool wave_active = __any(mask);

    float sigma = 0.0f, rr = 0.0f, rg = 0.0f, rb = 0.0f;

    // =========================== gather phase ===========================
    f16x8 facc[4];
    if (wave_active) {
        const float invR = 1.0f / RADIUS;
        const float px = (ox + t*dxn) * invR;
        const float py = (oy + t*dyn) * invR;
        const float pz = (oz + t*dzn) * invR;

        float cox = fminf(fmaxf((px+1.0f)*0.5f*127.0f, 0.0f), 127.0f);
        float coy = fminf(fmaxf((py+1.0f)*0.5f*127.0f, 0.0f), 127.0f);
        float coz = fminf(fmaxf((pz+1.0f)*0.5f*127.0f, 0.0f), 127.0f);
        int x0 = (int)floorf(cox); float fx = cox - (float)x0; int x1 = min(x0+1, 127);
        int y0 = (int)floorf(coy); float fy = coy - (float)y0; int y1 = min(y0+1, 127);
        int z0 = (int)floorf(coz); float fz = coz - (float)z0; int z1 = min(z0+1, 127);

        {
            const float wx0 = 1.0f-fx, wx1 = fx;
            const float wy0 = 1.0f-fy, wy1 = fy;
            const float wz0 = 1.0f-fz, wz1 = fz;
            const int i000 = (z0*128 + y0)*128 + x0;
            const int dxo = x1 - x0;
            const int dyo = (y1 - y0)*128;
            const int dzo = (z1 - z0)*16384;

            const f16x4 v000 = G1h[i000];
            const f16x4 v100 = G1h[i000 + dxo];
            const f16x4 v010 = G1h[i000 + dyo];
            const f16x4 v110 = G1h[i000 + dyo + dxo];
            const f16x4 v001 = G1h[i000 + dzo];
            const f16x4 v101 = G1h[i000 + dzo + dxo];
            const f16x4 v011 = G1h[i000 + dzo + dyo];
            const f16x4 v111 = G1h[i000 + dzo + dyo + dxo];

            const float w000 = wx0*wy0*wz0, w100 = wx1*wy0*wz0;
            const float w010 = wx0*wy1*wz0, w110 = wx1*wy1*wz0;
            const float w001 = wx0*wy0*wz1, w101 = wx1*wy0*wz1;
            const float w011 = wx0*wy1*wz1, w111 = wx1*wy1*wz1;

            float g[3];
            #pragma unroll
            for (int c = 0; c < 3; ++c) {
                g[c] = w000*(float)v000[c] + w100*(float)v100[c]
                     + w010*(float)v010[c] + w110*(float)v110[c]
                     + w001*(float)v001[c] + w101*(float)v101[c]
                     + w011*(float)v011[c] + w111*(float)v111[c];
            }

            cox = fminf(fmaxf((g[0]+1.0f)*0.5f*31.0f, 0.0f), 31.0f);
            coy = fminf(fmaxf((g[1]+1.0f)*0.5f*31.0f, 0.0f), 31.0f);
            coz = fminf(fmaxf((g[2]+1.0f)*0.5f*31.0f, 0.0f), 31.0f);
            x0 = (int)floorf(cox); fx = cox - (float)x0;
            y0 = (int)floorf(coy); fy = coy - (float)y0; y1 = min(y0+1, 31);
            z0 = (int)floorf(coz); fz = coz - (float)z0; z1 = min(z0+1, 31);
        }

        // ---- trilinear F: 4 corner-pairs, packed-f16 accumulate ----
        {
            const float wx0 = 1.0f-fx, wx1 = fx;   // at x0==31, fx==0 -> pad row unused
            const float wy0 = 1.0f-fy, wy1 = fy;
            const float wz0 = 1.0f-fz, wz1 = fz;
            const int j000 = (z0*32 + y0)*32 + x0;
            const int dyo = (y1 - y0)*32;
            const int dzo = (z1 - z0)*1024;

            const int   jp[4] = { j000, j000+dyo, j000+dzo, j000+dyo+dzo };
            const float ap[4] = { wy0*wz0, wy1*wz0, wy0*wz1, wy1*wz1 };

            #pragma unroll
            for (int q = 0; q < 4; ++q) facc[q] = (f16x8){};

            #pragma unroll
            for (int p = 0; p < 4; ++p) {
                const f16* base = Ft16 + (size_t)jp[p] * 32;
                const f16 ah = (f16)(ap[p]*wx0), bh = (f16)(ap[p]*wx1);
                const f16x8 av = {ah,ah,ah,ah,ah,ah,ah,ah};
                const f16x8 bv = {bh,bh,bh,bh,bh,bh,bh,bh};
                #pragma unroll
                for (int q = 0; q < 4; ++q) {
                    const f16x8 lo = *(const f16x8*)(base + q*8);
                    const f16x8 hi = *(const f16x8*)(base + 32 + q*8);
                    facc[q] += av * lo;       // v_pk_fma_f16
                    facc[q] += bv * hi;
                }
            }
        }

        // ---- stage feats to LDS (wave-private rows; same-wave DS in-order,
        //      so NO block barrier needed) ----
        #pragma unroll
        for (int gq = 0; gq < 4; ++gq)
            *(f16x8*)&feats_lds[tid][gq*8] = facc[gq];
    }

    // ---- MFMA phase: each wave computes its own 64 samples ----
    if (wave_active) {
        const int lane15 = lane & 15;
        const int laneg  = lane >> 4;

        float bias_d[4], bias_c[4], wd2v[4];
        float wc2r[4], wc2g[4], wc2b[4];
        #pragma unroll
        for (int nt = 0; nt < 4; ++nt) {
            const int j = nt*16 + lane15;
            bias_d[nt] = bd1[j];
            bias_c[nt] = bc1[j] + dxn*Wc1[32*64+j] + dyn*Wc1[33*64+j] + dzn*Wc1[34*64+j];
            wd2v[nt]   = Wd2[j];
            wc2r[nt]   = Wc2[j*3+0];
            wc2g[nt]   = Wc2[j*3+1];
            wc2b[nt]   = Wc2[j*3+2];
        }
        f16x8 bdf[4], bcf[4];
        #pragma unroll
        for (int nt = 0; nt < 4; ++nt) {
            bdf[nt] = *(const f16x8*)(Bd + ((size_t)(nt*64+lane))*8);
            bcf[nt] = *(const f16x8*)(Bc + ((size_t)(nt*64+lane))*8);
        }

        #pragma unroll
        for (int mt = 0; mt < 4; ++mt) {
            const int arow = wv*64 + mt*16 + lane15;
            const f16x8 af = *(const f16x8*)&feats_lds[arow][laneg*8];

            f32x4 accd[4], accc[4];
            #pragma unroll
            for (int nt = 0; nt < 4; ++nt) {
                const float bdv = bias_d[nt], bcv = bias_c[nt];
                accd[nt] = (f32x4){bdv, bdv, bdv, bdv};
                accc[nt] = (f32x4){bcv, bcv, bcv, bcv};
            }
            #pragma unroll
            for (int nt = 0; nt < 4; ++nt) {
                accd[nt] = __builtin_amdgcn_mfma_f32_16x16x32_f16(af, bdf[nt], accd[nt], 0, 0, 0);
                accc[nt] = __builtin_amdgcn_mfma_f32_16x16x32_f16(af, bcf[nt], accc[nt], 0, 0, 0);
            }

            // layer-2: per-lane f32 partials, then packed-f16x2 16-lane reduce
            float ss[4] = {0.f,0.f,0.f,0.f};
            float sr[4] = {0.f,0.f,0.f,0.f};
            float sg[4] = {0.f,0.f,0.f,0.f};
            float sb[4] = {0.f,0.f,0.f,0.f};
            #pragma unroll
            for (int nt = 0; nt < 4; ++nt) {
                #pragma unroll
                for (int reg = 0; reg < 4; ++reg) {
                    const float hd = fmaxf(accd[nt][reg], 0.0f);
                    ss[reg] += hd * wd2v[nt];
                    const float hc = fmaxf(accc[nt][reg], 0.0f);
                    sr[reg] += hc * wc2r[nt];
                    sg[reg] += hc * wc2g[nt];
                    sb[reg] += hc * wc2b[nt];
                }
            }
            f16x2 pa[4], pb[4];
            #pragma unroll
            for (int reg = 0; reg < 4; ++reg) {
                pa[reg] = (f16x2){(f16)ss[reg], (f16)sr[reg]};
                pb[reg] = (f16x2){(f16)sg[reg], (f16)sb[reg]};
            }
            #pragma unroll
            for (int st = 1; st < 16; st <<= 1) {
                #pragma unroll
                for (int reg = 0; reg < 4; ++reg) {
                    pa[reg] += shfl_xor_h2(pa[reg], st);   // v_pk_add_f16
                    pb[reg] += shfl_xor_h2(pb[reg], st);
                }
            }
            if (lane15 == 0) {
                const int base = wv*64 + mt*16 + laneg*4;  // D row = (lane>>4)*4 + reg
                #pragma unroll
                for (int reg = 0; reg < 4; ++reg) {
                    sig_lds[base+reg]    = (float)pa[reg][0];
                    rgb_lds[base+reg][0] = pa[reg][1];
                    rgb_lds[base+reg][1] = pb[reg][0];
                    rgb_lds[base+reg][2] = pb[reg][1];
                }
            }
        }
    }
    // (no block barrier: sig/rgb rows are wave-private, same-wave DS in-order)

    // ---- owner pick-up ----
    {
        const float sv  = sig_lds[tid];
        const float crv = (float)rgb_lds[tid][0] + bc2[0];
        const float cgv = (float)rgb_lds[tid][1] + bc2[1];
        const float cbv = (float)rgb_lds[tid][2] + bc2[2];
        sigma = mask ? (sv + bd2[0]) : 0.0f;
        rr = mask ? 1.0f/(1.0f + __expf(-crv)) : 0.0f;
        rg = mask ? 1.0f/(1.0f + __expf(-cgv)) : 0.0f;
        rb = mask ? 1.0f/(1.0f + __expf(-cbv)) : 0.0f;
    }

    // ---- alpha, exclusive product scan (T_excl), weights ----
    const float alpha = 1.0f - __expf(-fmaxf(sigma, 0.0f) * STEP);
    float p = 1.0f - alpha + 1e-10f;

    float scan = p;
    #pragma unroll
    for (int off = 1; off < 64; off <<= 1) {
        const float n = __shfl_up(scan, off, 64);
        if (lane >= off) scan *= n;
    }
    if (lane == 63) s_wtot[wv] = scan;
    __syncthreads();

    float pre = 1.0f;
    #pragma unroll
    for (int q = 0; q < 4; ++q) if (q < wv) pre *= s_wtot[q];
    float excl = __shfl_up(scan, 1, 64);
    if (lane == 0) excl = 1.0f;
    const float Texcl = pre * excl;

    const float w = alpha * Texcl;
    float sw  = w;
    float swr = w * rr, swg = w * rg, swb = w * rb;

    // ---- block reduction ----
    #pragma unroll
    for (int off = 32; off > 0; off >>= 1) {
        sw  += __shfl_down(sw,  off, 64);
        swr += __shfl_down(swr, off, 64);
        swg += __shfl_down(swg, off, 64);
        swb += __shfl_down(swb, off, 64);
    }
    if (lane == 0) {
        s_red[wv][0] = sw;  s_red[wv][1] = swr;
        s_red[wv][2] = swg; s_red[wv][3] = swb;
    }
    __syncthreads();
    if (tid == 0) {
        float W = 0.0f, R = 0.0f, Gc = 0.0f, Bc_ = 0.0f;
        #pragma unroll
        for (int q = 0; q < 4; ++q) {
            W  += s_red[q][0]; R  += s_red[q][1];
            Gc += s_red[q][2]; Bc_ += s_red[q][3];
        }
        const float bg = 1.0f - W;
        out[b*3+0] = R   + bg;
        out[b*3+1] = Gc  + bg;
        out[b*3+2] = Bc_ + bg;
    }
}

// ================= fallback: fp32 per-thread everything (no workspace) =======
__global__ __launch_bounds__(256) __attribute__((amdgpu_waves_per_eu(2, 6)))
void nerf_fused_naive(
    const float* __restrict__ rays_o, const float* __restrict__ rays_d,
    const float* __restrict__ G1, const float* __restrict__ Fg,
    const float* __restrict__ Wd1, const float* __restrict__ bd1,
    const float* __restrict__ Wd2, const float* __restrict__ bd2,
    const float* __restrict__ Wc1, const float* __restrict__ bc1,
    const float* __restrict__ Wc2, const float* __restrict__ bc2,
    float* __restrict__ out)
{
    const float RADIUS = 1.3f;
    const float STEP = 0.0176f;

    const int b    = blockIdx.x;
    const int tid  = threadIdx.x;
    const int lane = tid & 63;
    const int wv   = tid >> 6;

    __shared__ float s_wtot[4];
    __shared__ float s_red[4][4];

    const float ox = rays_o[b*3+0], oy = rays_o[b*3+1], oz = rays_o[b*3+2];
    const float rdx = rays_d[b*3+0], rdy = rays_d[b*3+1], rdz = rays_d[b*3+2];
    const float rn  = sqrtf(rdx*rdx + rdy*rdy + rdz*rdz);
    const float dxn = rdx/rn, dyn = rdy/rn, dzn = rdz/rn;

    float sd, inv, t1, t2, tmin, tmax;
    sd = (fabsf(dxn) < 1e-9f) ? 1e-9f : dxn; inv = 1.0f/sd;
    t1 = (-RADIUS - ox)*inv; t2 = (RADIUS - ox)*inv;
    tmin = fminf(t1,t2); tmax = fmaxf(t1,t2);
    sd = (fabsf(dyn) < 1e-9f) ? 1e-9f : dyn; inv = 1.0f/sd;
    t1 = (-RADIUS - oy)*inv; t2 = (RADIUS - oy)*inv;
    tmin = fmaxf(tmin, fminf(t1,t2)); tmax = fminf(tmax, fmaxf(t1,t2));
    sd = (fabsf(dzn) < 1e-9f) ? 1e-9f : dzn; inv = 1.0f/sd;
    t1 = (-RADIUS - oz)*inv; t2 = (RADIUS - oz)*inv;
    tmin = fmaxf(tmin, fminf(t1,t2)); tmax = fminf(tmax, fmaxf(t1,t2));

    const float tnear = fmaxf(tmin, 0.0f);
    const bool  hit   = tmax > tnear;
    const float t     = tnear + STEP * (float)tid;
    const bool  mask  = (t < tmax) && hit;

    float sigma = 0.0f, rr = 0.0f, rg = 0.0f, rb = 0.0f;

    if (__any(mask)) {
        const float invR = 1.0f / RADIUS;
        const float px = (ox + t*dxn) * invR;
        const float py = (oy + t*dyn) * invR;
        const float pz = (oz + t*dzn) * invR;

        float cox = fminf(fmaxf((px+1.0f)*0.5f*127.0f, 0.0f), 127.0f);
        float coy = fminf(fmaxf((py+1.0f)*0.5f*127.0f, 0.0f), 127.0f);
        float coz = fminf(fmaxf((pz+1.0f)*0.5f*127.0f, 0.0f), 127.0f);
        int x0 = (int)floorf(cox); float fx = cox - (float)x0; int x1 = min(x0+1, 127);
        int y0 = (int)floorf(coy); float fy = coy - (float)y0; int y1 = min(y0+1, 127);
        int z0 = (int)floorf(coz); float fz = coz - (float)z0; int z1 = min(z0+1, 127);

        float feats[32];
        {
            const float wx0 = 1.0f-fx, wx1 = fx;
            const float wy0 = 1.0f-fy, wy1 = fy;
            const float wz0 = 1.0f-fz, wz1 = fz;
            const float w000 = wx0*wy0*wz0, w100 = wx1*wy0*wz0;
            const float w010 = wx0*wy1*wz0, w110 = wx1*wy1*wz0;
            const float w001 = wx0*wy0*wz1, w101 = wx1*wy0*wz1;
            const float w011 = wx0*wy1*wz1, w111 = wx1*wy1*wz1;
            const int i000 = (z0*128 + y0)*128 + x0;
            const int dxo = x1 - x0;
            const int dyo = (y1 - y0)*128;
            const int dzo = (z1 - z0)*16384;
            const int i100 = i000 + dxo,       i010 = i000 + dyo;
            const int i110 = i000 + dyo + dxo, i001 = i000 + dzo;
            const int i101 = i000 + dzo + dxo, i011 = i000 + dzo + dyo;
            const int i111 = i000 + dzo + dyo + dxo;

            float g[3];
            #pragma unroll
            for (int c = 0; c < 3; ++c) {
                const float* gp = G1 + (size_t)c * 2097152;
                g[c] = w000*gp[i000] + w100*gp[i100] + w010*gp[i010] + w110*gp[i110]
                     + w001*gp[i001] + w101*gp[i101] + w011*gp[i011] + w111*gp[i111];
            }

            cox = fminf(fmaxf((g[0]+1.0f)*0.5f*31.0f, 0.0f), 31.0f);
            coy = fminf(fmaxf((g[1]+1.0f)*0.5f*31.0f, 0.0f), 31.0f);
            coz = fminf(fmaxf((g[2]+1.0f)*0.5f*31.0f, 0.0f), 31.0f);
            x0 = (int)floorf(cox); fx = cox - (float)x0; x1 = min(x0+1, 31);
            y0 = (int)floorf(coy); fy = coy - (float)y0; y1 = min(y0+1, 31);
            z0 = (int)floorf(coz); fz = coz - (float)z0; z1 = min(z0+1, 31);

            const float vx0 = 1.0f-fx, vx1 = fx;
            const float vy0 = 1.0f-fy, vy1 = fy;
            const float vz0 = 1.0f-fz, vz1 = fz;
            const float u000 = vx0*vy0*vz0, u100 = vx1*vy0*vz0;
            const float u010 = vx0*vy1*vz0, u110 = vx1*vy1*vz0;
            const float u001 = vx0*vy0*vz1, u101 = vx1*vy0*vz1;
            const float u011 = vx0*vy1*vz1, u111 = vx1*vy1*vz1;
            const int j000 = (z0*32 + y0)*32 + x0;
            const int exo = x1 - x0;
            const int eyo = (y1 - y0)*32;
            const int ezo = (z1 - z0)*1024;
            const int j100 = j000 + exo,       j010 = j000 + eyo;
            const int j110 = j000 + eyo + exo, j001 = j000 + ezo;
            const int j101 = j000 + ezo + exo, j011 = j000 + ezo + eyo;
            const int j111 = j000 + ezo + eyo + exo;

            #pragma unroll
            for (int c = 0; c < 32; ++c) {
                const float* fp = Fg + (size_t)c * 32768;
                feats[c] = u000*fp[j000] + u100*fp[j100] + u010*fp[j010] + u110*fp[j110]
                         + u001*fp[j001] + u101*fp[j101] + u011*fp[j011] + u111*fp[j111];
            }
        }

        float sg1 = bd2[0], cr = 0.0f, cg = 0.0f, cb = 0.0f;
        for (int j0 = 0; j0 < 64; j0 += 8) {
            float ad[8], ac[8];
            #pragma unroll
            for (int jj = 0; jj < 8; ++jj) {
                ad[jj] = bd1[j0+jj];
                ac[jj] = bc1[j0+jj] + dxn*Wc1[32*64 + j0 + jj]
                                    + dyn*Wc1[33*64 + j0 + jj]
                                    + dzn*Wc1[34*64 + j0 + jj];
            }
            #pragma unroll
            for (int k = 0; k < 32; ++k) {
                const float fv = feats[k];
                #pragma unroll
                for (int jj = 0; jj < 8; ++jj) {
                    ad[jj] += fv * Wd1[k*64 + j0 + jj];
                    ac[jj] += fv * Wc1[k*64 + j0 + jj];
                }
            }
            #pragma unroll
            for (int jj = 0; jj < 8; ++jj) {
                sg1 += fmaxf(ad[jj], 0.0f) * Wd2[j0+jj];
                const float hc = fmaxf(ac[jj], 0.0f);
                cr += hc * Wc2[(j0+jj)*3 + 0];
                cg += hc * Wc2[(j0+jj)*3 + 1];
                cb += hc * Wc2[(j0+jj)*3 + 2];
            }
        }
        cr += bc2[0]; cg += bc2[1]; cb += bc2[2];
        sigma = mask ? sg1 : 0.0f;
        rr = mask ? 1.0f/(1.0f + expf(-cr)) : 0.0f;
        rg = mask ? 1.0f/(1.0f + expf(-cg)) : 0.0f;
        rb = mask ? 1.0f/(1.0f + expf(-cb)) : 0.0f;
    }

    const float alpha = 1.0f - expf(-fmaxf(sigma, 0.0f) * STEP);
    float p = 1.0f - alpha + 1e-10f;

    float scan = p;
    #pragma unroll
    for (int off = 1; off < 64; off <<= 1) {
        const float n = __shfl_up(scan, off, 64);
        if (lane >= off) scan *= n;
    }
    if (lane == 63) s_wtot[wv] = scan;
    __syncthreads();

    float pre = 1.0f;
    #pragma unroll
    for (int q = 0; q < 4; ++q) if (q < wv) pre *= s_wtot[q];
    float excl = __shfl_up(scan, 1, 64);
    if (lane == 0) excl = 1.0f;
    const float Texcl = pre * excl;

    const float w = alpha * Texcl;
    float sw  = w;
    float swr = w * rr, swg = w * rg, swb = w * rb;

    #pragma unroll
    for (int off = 32; off > 0; off >>= 1) {
        sw  += __shfl_down(sw,  off, 64);
        swr += __shfl_down(swr, off, 64);
        swg += __shfl_down(swg, off, 64);
        swb += __shfl_down(swb, off, 64);
    }
    if (lane == 0) {
        s_red[wv][0] = sw;  s_red[wv][1] = swr;
        s_red[wv][2] = swg; s_red[wv][3] = swb;
    }
    __syncthreads();
    if (tid == 0) {
        float W = 0.0f, R = 0.0f, Gc = 0.0f, Bc_ = 0.0f;
        #pragma unroll
        for (int q = 0; q < 4; ++q) {
            W  += s_red[q][0]; R  += s_red[q][1];
            Gc += s_red[q][2]; Bc_ += s_red[q][3];
        }
        const float bg = 1.0f - W;
        out[b*3+0] = R   + bg;
        out[b*3+1] = Gc  + bg;
        out[b*3+2] = Bc_ + bg;
    }
}

extern "C" void kernel_launch(void* const* d_in, const int* in_sizes, int n_in,
                              void* d_out, int out_size, void* d_ws, size_t ws_size,
                              hipStream_t stream) {
    const float* rays_o = (const float*)d_in[0];
    const float* rays_d = (const float*)d_in[1];
    const float* G1     = (const float*)d_in[2];
    const float* Fg     = (const float*)d_in[3];
    const float* Wd1    = (const float*)d_in[4];
    const float* bd1    = (const float*)d_in[5];
    const float* Wd2    = (const float*)d_in[6];
    const float* bd2    = (const float*)d_in[7];
    const float* Wc1    = (const float*)d_in[8];
    const float* bc1    = (const float*)d_in[9];
    const float* Wc2    = (const float*)d_in[10];
    const float* bc2    = (const float*)d_in[11];
    float* out = (float*)d_out;

    const int B = in_sizes[0] / 3;   // 2048 rays
    const size_t ft16_bytes = (size_t)32769 * 32 * sizeof(f16);    // ~2.1 MB (incl pad)
    const size_t g1h_bytes  = (size_t)2097152 * sizeof(f16x4);     // 16.8 MB
    const size_t bf_bytes   = (size_t)4 * 64 * 8 * sizeof(f16);    // 4 KB each

    if (ws_size >= ft16_bytes + g1h_bytes + 2*bf_bytes) {
        f16*   Ft16 = (f16*)d_ws;
        f16x4* G1h  = (f16x4*)((char*)d_ws + ft16_bytes);
        f16*   Bd   = (f16*)((char*)d_ws + ft16_bytes + g1h_bytes);
        f16*   Bc   = (f16*)((char*)d_ws + ft16_bytes + g1h_bytes + bf_bytes);
        transpose_F16<<<dim3(128), dim3(256), 0, stream>>>(Fg, Ft16);
        transpose_G1h<<<dim3(8192), dim3(256), 0, stream>>>(G1, G1h);
        pack_bfrags<<<dim3(1), dim3(256), 0, stream>>>(Wd1, Wc1, Bd, Bc);
        nerf_fused_opt<<<dim3(B), dim3(NSAMP), 0, stream>>>(
            rays_o, rays_d, G1h, Ft16, bd1, Wd2, bd2, Wc1, bc1, Wc2, bc2,
            Bd, Bc, out);
    } else {
        nerf_fused_naive<<<dim3(B), dim3(NSAMP), 0, stream>>>(
            rays_o, rays_d, G1, Fg, Wd1, bd1, Wd2, bd2, Wc1, bc1, Wc2, bc2, out);
    }
}